// Round 10
// baseline (873.356 us; speedup 1.0000x reference)
//
#include <hip/hip_runtime.h>

// PWC-Net cost volume, fp32. B=4, C=128, H=256, W=448, 81 shifts.
// out[b, di*9+dj, h, w] = (1/128) * sum_c feat1[b,c,h,w] * feat2[b,c,h+di-4,w+dj-4]
//
// Barrier-free, LDS-free. One wave per (b,h,di) (9216 waves). Lane owns 8 px
// (m = lane, 56 active). Per channel each lane loads only its own 8 feat1 +
// 8 feat2 floats (4x b128, fully coalesced, zero inter-lane overlap); the
// 16-float window = left4 | own8 | right4 via 8 ds_bpermute from neighbor
// lanes (crossbar only — no LDS storage, no barriers). Edge-lane garbage
// lands only in acc slots whose output is defined 0 -> masked at store.
// Vertical OOB rows are wave-uniform: store zeros, exit.
//
// Pipeline: 3 rotating prefetch sets, load->use distance = 2 bodies
// (~1400 cy, covers HBM-miss latency); period-3 unroll -> zero reg moves.

typedef __attribute__((ext_vector_type(4))) float f32x4;

__device__ __forceinline__ float bperm(int idx, float v) {
    return __int_as_float(__builtin_amdgcn_ds_bpermute(idx, __float_as_int(v)));
}

__global__ __launch_bounds__(256, 3) void cv_kernel(
    const float* __restrict__ feat1,
    const float* __restrict__ feat2,
    float* __restrict__ out)
{
    constexpr int C = 128, H = 256, W = 448;
    constexpr unsigned HW = (unsigned)(H * W);

    const int tid  = threadIdx.x;
    const int wid  = tid >> 6;
    const int lane = tid & 63;

    // 2304 blocks = 8 * 288: XCD-contiguous item mapping (bijective).
    const int swz  = (blockIdx.x & 7) * 288 + (blockIdx.x >> 3);
    const int item = swz * 4 + wid;          // 0..9215
    const int di   = item % 9;
    const int bh   = item / 9;
    const int h    = bh & 255;
    const int b    = bh >> 8;

    const int m   = (lane < 56) ? lane : 55;
    const int px0 = m << 3;
    const int hr  = h + di - 4;

    float* ob = out + (((size_t)(b * 81 + di * 9)) * H + h) * W + px0;

    if (hr < 0 || hr >= H) {                 // wave-uniform: whole row zero
        if (lane < 56) {
            const f32x4 z = {0.f, 0.f, 0.f, 0.f};
#pragma unroll
            for (int dj = 0; dj < 9; ++dj) {
                *(f32x4*)(ob + (size_t)dj * HW)     = z;
                *(f32x4*)(ob + (size_t)dj * HW + 4) = z;
            }
        }
        return;
    }

    unsigned f1o = (unsigned)(((b * C * H) + h) * W + px0);   // float index
    unsigned f2o = (unsigned)(((b * C * H) + hr) * W + px0);

    const int idxL = ((lane - 1) & 63) << 2;  // pull from lane m-1
    const int idxR = ((lane + 1) & 63) << 2;  // pull from lane m+1

    float acc[9][8];
#pragma unroll
    for (int j = 0; j < 9; ++j)
#pragma unroll
        for (int p = 0; p < 8; ++p) acc[j][p] = 0.0f;

#define LOADSET(A0, A1, B0, B1) do { \
    A0 = *(const f32x4*)(feat1 + f1o); \
    A1 = *(const f32x4*)(feat1 + f1o + 4); \
    B0 = *(const f32x4*)(feat2 + f2o); \
    B1 = *(const f32x4*)(feat2 + f2o + 4); \
    f1o += HW; f2o += HW; } while (0)

#define COMPSET(A0, A1, B0, B1) do { \
    const float w[16] = { \
        bperm(idxL, B1.x), bperm(idxL, B1.y), bperm(idxL, B1.z), bperm(idxL, B1.w), \
        B0.x, B0.y, B0.z, B0.w, B1.x, B1.y, B1.z, B1.w, \
        bperm(idxR, B0.x), bperm(idxR, B0.y), bperm(idxR, B0.z), bperm(idxR, B0.w)}; \
    const float a[8] = {A0.x, A0.y, A0.z, A0.w, A1.x, A1.y, A1.z, A1.w}; \
    _Pragma("unroll") \
    for (int dj = 0; dj < 9; ++dj) { \
        _Pragma("unroll") \
        for (int p = 0; p < 8; ++p) \
            acc[dj][p] = fmaf(a[p], w[dj + p], acc[dj][p]); \
    } } while (0)

    // 3 rotating sets; load->use distance = 2 compute bodies.
    f32x4 xa0, xa1, xb0, xb1;   // set 0
    f32x4 ya0, ya1, yb0, yb1;   // set 1
    f32x4 za0, za1, zb0, zb1;   // set 2

    LOADSET(xa0, xa1, xb0, xb1);            // ch 0
    LOADSET(ya0, ya1, yb0, yb1);            // ch 1

    for (int g = 0; g < 42; ++g) {          // channels 3g .. 3g+2
        LOADSET(za0, za1, zb0, zb1);        // ch 3g+2
        COMPSET(xa0, xa1, xb0, xb1);        // ch 3g
        LOADSET(xa0, xa1, xb0, xb1);        // ch 3g+3
        COMPSET(ya0, ya1, yb0, yb1);        // ch 3g+1
        LOADSET(ya0, ya1, yb0, yb1);        // ch 3g+4
        COMPSET(za0, za1, zb0, zb1);        // ch 3g+2
    }
    COMPSET(xa0, xa1, xb0, xb1);            // ch 126
    COMPSET(ya0, ya1, yb0, yb1);            // ch 127

#undef LOADSET
#undef COMPSET

    if (lane < 56) {
        const float s = 1.0f / 128.0f;
#pragma unroll
        for (int dj = 0; dj < 9; ++dj) {
            float o[8];
#pragma unroll
            for (int p = 0; p < 8; ++p) {
                float v = acc[dj][p] * s;
                // out col = px0 + p + dj - 4: zero where col<0 (m==0, p+dj<4)
                // or col>447 (m==55, p+dj>11) — garbage-fed slots.
                if (dj + p < 4)  v = (m == 0)  ? 0.f : v;
                if (dj + p > 11) v = (m == 55) ? 0.f : v;
                o[p] = v;
            }
            f32x4 o0 = {o[0], o[1], o[2], o[3]};
            f32x4 o1 = {o[4], o[5], o[6], o[7]};
            *(f32x4*)(ob + (size_t)dj * HW)     = o0;
            *(f32x4*)(ob + (size_t)dj * HW + 4) = o1;
        }
    }
}

extern "C" void kernel_launch(void* const* d_in, const int* in_sizes, int n_in,
                              void* d_out, int out_size, void* d_ws, size_t ws_size,
                              hipStream_t stream) {
    const float* feat1 = (const float*)d_in[0];
    const float* feat2 = (const float*)d_in[1];
    float* out = (float*)d_out;
    cv_kernel<<<dim3(2304), dim3(256), 0, stream>>>(feat1, feat2, out);
}

// Round 11
// 320.328 us; speedup vs baseline: 2.7264x; 2.7264x over previous
//
#include <hip/hip_runtime.h>

// PWC-Net cost volume, fp32. B=4, C=128, H=256, W=448, 81 shifts.
// out[b, di*9+dj, h, w] = (1/128) * sum_c feat1[b,c,h,w] * feat2[b,c,h+di-4,w+dj-4]
//
// Barrier-free, LDS-free, TLP-first. One wave per (b,h,di,half): 18432 waves.
// Lane owns 4 px (group G = half*56 + lane, 56 active lanes). Per channel a
// lane loads ONE feat1 quad + ONE feat2 quad (b128, coalesced, no overlap);
// window cols 4G-4..4G+7 = left quad | own quad | right quad, neighbors via
// 8 ds_bpermute (crossbar only). Half-boundary neighbors: lanes 56/57 load
// the adjacent groups so the pull stays in-wave. Edge garbage (G==0 left,
// G==111 right) only feeds outputs defined 0 -> masked at store. Vertical
// OOB rows wave-uniform: store zeros, exit. Distance-1 register prefetch.
// acc[9][4]=36 regs -> ~80 total -> ~6 waves/SIMD latency hiding.

typedef __attribute__((ext_vector_type(4))) float f32x4;

__device__ __forceinline__ float bperm(int idx, float v) {
    return __int_as_float(__builtin_amdgcn_ds_bpermute(idx, __float_as_int(v)));
}

__global__ __launch_bounds__(256, 4) void cv_kernel(
    const float* __restrict__ feat1,
    const float* __restrict__ feat2,
    float* __restrict__ out)
{
    constexpr int C = 128, H = 256, W = 448;
    constexpr unsigned HW = (unsigned)(H * W);

    const int tid  = threadIdx.x;
    const int wid  = tid >> 6;
    const int lane = tid & 63;

    // 4608 blocks = 8 * 576: XCD-contiguous item mapping (bijective).
    const int swz   = (blockIdx.x & 7) * 576 + (blockIdx.x >> 3);
    const int item2 = swz * 4 + wid;          // 0..18431
    const int half  = item2 & 1;
    const int item  = item2 >> 1;             // 0..9215
    const int di    = item % 9;
    const int bh    = item / 9;
    const int h     = bh & 255;
    const int b     = bh >> 8;

    const int mg = (lane < 56) ? lane : 55;   // local group 0..55
    const int G  = half * 56 + mg;            // global group 0..111
    const int hr = h + di - 4;

    float* ob = out + (((size_t)(b * 81 + di * 9)) * H + h) * W + G * 4;

    if (hr < 0 || hr >= H) {                  // wave-uniform: whole row zero
        if (lane < 56) {
            const f32x4 z = {0.f, 0.f, 0.f, 0.f};
#pragma unroll
            for (int dj = 0; dj < 9; ++dj)
                *(f32x4*)(ob + (size_t)dj * HW) = z;
        }
        return;
    }

    // Load-group: lanes 0..55 own; 56 = right-boundary; 57 = left-boundary.
    int gload;
    if (half == 0) gload = (lane < 56) ? lane : (lane == 56 ? 56 : (lane == 57 ? 0 : 55));
    else           gload = (lane < 56) ? 56 + lane : (lane == 56 ? 111 : (lane == 57 ? 55 : 60));

    unsigned f1o = (unsigned)(((b * C * H) + h) * W + gload * 4);
    unsigned f2o = (unsigned)(((b * C * H) + hr) * W + gload * 4);

    const int idxL = ((lane == 0)  ? 57 : lane - 1) << 2;
    const int idxR = ((lane == 55) ? 56 : lane + 1) << 2;

    float acc[9][4];
#pragma unroll
    for (int j = 0; j < 9; ++j)
#pragma unroll
        for (int p = 0; p < 4; ++p) acc[j][p] = 0.0f;

    // Distance-1 prefetch (R8 structure: 2 live sets only).
    f32x4 ca = *(const f32x4*)(feat1 + f1o);
    f32x4 cb = *(const f32x4*)(feat2 + f2o);
    f1o += HW; f2o += HW;

    for (int t = 0; t < C - 1; ++t) {
        const f32x4 na = *(const f32x4*)(feat1 + f1o);
        const f32x4 nb = *(const f32x4*)(feat2 + f2o);
        f1o += HW; f2o += HW;

        const float w[12] = {
            bperm(idxL, cb.x), bperm(idxL, cb.y), bperm(idxL, cb.z), bperm(idxL, cb.w),
            cb.x, cb.y, cb.z, cb.w,
            bperm(idxR, cb.x), bperm(idxR, cb.y), bperm(idxR, cb.z), bperm(idxR, cb.w)};
        const float a[4] = {ca.x, ca.y, ca.z, ca.w};
#pragma unroll
        for (int dj = 0; dj < 9; ++dj)
#pragma unroll
            for (int p = 0; p < 4; ++p)
                acc[dj][p] = fmaf(a[p], w[dj + p], acc[dj][p]);

        ca = na; cb = nb;
    }
    {   // last channel
        const float w[12] = {
            bperm(idxL, cb.x), bperm(idxL, cb.y), bperm(idxL, cb.z), bperm(idxL, cb.w),
            cb.x, cb.y, cb.z, cb.w,
            bperm(idxR, cb.x), bperm(idxR, cb.y), bperm(idxR, cb.z), bperm(idxR, cb.w)};
        const float a[4] = {ca.x, ca.y, ca.z, ca.w};
#pragma unroll
        for (int dj = 0; dj < 9; ++dj)
#pragma unroll
            for (int p = 0; p < 4; ++p)
                acc[dj][p] = fmaf(a[p], w[dj + p], acc[dj][p]);
    }

    if (lane < 56) {
        const float s = 1.0f / 128.0f;
        const bool leftEdge  = (G == 0);
        const bool rightEdge = (G == 111);
#pragma unroll
        for (int dj = 0; dj < 9; ++dj) {
            float o[4];
#pragma unroll
            for (int p = 0; p < 4; ++p) {
                float v = acc[dj][p] * s;
                // out col = 4G + p + dj - 4: left quad garbage -> dj+p<4,
                // right quad garbage -> dj+p>7 (col>447 only at G==111).
                if (dj + p < 4) v = leftEdge  ? 0.f : v;
                if (dj + p > 7) v = rightEdge ? 0.f : v;
                o[p] = v;
            }
            f32x4 ov = {o[0], o[1], o[2], o[3]};
            *(f32x4*)(ob + (size_t)dj * HW) = ov;
        }
    }
}

extern "C" void kernel_launch(void* const* d_in, const int* in_sizes, int n_in,
                              void* d_out, int out_size, void* d_ws, size_t ws_size,
                              hipStream_t stream) {
    const float* feat1 = (const float*)d_in[0];
    const float* feat2 = (const float*)d_in[1];
    float* out = (float*)d_out;
    cv_kernel<<<dim3(4608), dim3(256), 0, stream>>>(feat1, feat2, out);
}

// Round 12
// 309.632 us; speedup vs baseline: 2.8206x; 1.0345x over previous
//
#include <hip/hip_runtime.h>

// PWC-Net cost volume, fp32. B=4, C=128, H=256, W=448, 81 shifts.
// out[b, di*9+dj, h, w] = (1/128) * sum_c feat1[b,c,h,w] * feat2[b,c,h+di-4,w+dj-4]
//
// Barrier-free, LDS-free, TLP+ILP. One wave per (b,h,di,half): 18432 waves.
// Lane owns 4 px (group G = half*56 + lane, 56 active). Per channel a lane
// loads ONE feat1 quad + ONE feat2 quad (b128, coalesced, no overlap);
// window cols 4G-4..4G+7 = left|own|right quads, neighbors via 8 ds_bpermute
// (crossbar only). Lanes 56/57 load boundary groups so pulls stay in-wave.
// Edge garbage masked at store. OOB rows wave-uniform: store zeros, exit.
//
// Pipeline: DISTANCE-2 register prefetch, 3 rotating sets (x,y,z), period-3
// unrolled -> zero reg moves. Live ~100 regs (acc 36 + 24 prefetch): no
// spill (R9's spill was at acc=72), occupancy stays ~22 waves/CU.

typedef __attribute__((ext_vector_type(4))) float f32x4;

__device__ __forceinline__ float bperm(int idx, float v) {
    return __int_as_float(__builtin_amdgcn_ds_bpermute(idx, __float_as_int(v)));
}

__global__ __launch_bounds__(256, 4) void cv_kernel(
    const float* __restrict__ feat1,
    const float* __restrict__ feat2,
    float* __restrict__ out)
{
    constexpr int C = 128, H = 256, W = 448;
    constexpr unsigned HW = (unsigned)(H * W);

    const int tid  = threadIdx.x;
    const int wid  = tid >> 6;
    const int lane = tid & 63;

    // 4608 blocks = 8 * 576: XCD-contiguous item mapping (bijective).
    const int swz   = (blockIdx.x & 7) * 576 + (blockIdx.x >> 3);
    const int item2 = swz * 4 + wid;          // 0..18431
    const int half  = item2 & 1;
    const int item  = item2 >> 1;             // 0..9215
    const int di    = item % 9;
    const int bh    = item / 9;
    const int h     = bh & 255;
    const int b     = bh >> 8;

    const int mg = (lane < 56) ? lane : 55;   // local group 0..55
    const int G  = half * 56 + mg;            // global group 0..111
    const int hr = h + di - 4;

    float* ob = out + (((size_t)(b * 81 + di * 9)) * H + h) * W + G * 4;

    if (hr < 0 || hr >= H) {                  // wave-uniform: whole row zero
        if (lane < 56) {
            const f32x4 z = {0.f, 0.f, 0.f, 0.f};
#pragma unroll
            for (int dj = 0; dj < 9; ++dj)
                *(f32x4*)(ob + (size_t)dj * HW) = z;
        }
        return;
    }

    // Load-group: lanes 0..55 own; 56 = right-boundary; 57 = left-boundary.
    int gload;
    if (half == 0) gload = (lane < 56) ? lane : (lane == 56 ? 56 : (lane == 57 ? 0 : 55));
    else           gload = (lane < 56) ? 56 + lane : (lane == 56 ? 111 : (lane == 57 ? 55 : 60));

    unsigned f1o = (unsigned)(((b * C * H) + h) * W + gload * 4);
    unsigned f2o = (unsigned)(((b * C * H) + hr) * W + gload * 4);

    const int idxL = ((lane == 0)  ? 57 : lane - 1) << 2;
    const int idxR = ((lane == 55) ? 56 : lane + 1) << 2;

    float acc[9][4];
#pragma unroll
    for (int j = 0; j < 9; ++j)
#pragma unroll
        for (int p = 0; p < 4; ++p) acc[j][p] = 0.0f;

#define LOADSET(A, Bv) do { \
    A  = *(const f32x4*)(feat1 + f1o); \
    Bv = *(const f32x4*)(feat2 + f2o); \
    f1o += HW; f2o += HW; } while (0)

#define COMPSET(A, Bv) do { \
    const float w[12] = { \
        bperm(idxL, Bv.x), bperm(idxL, Bv.y), bperm(idxL, Bv.z), bperm(idxL, Bv.w), \
        Bv.x, Bv.y, Bv.z, Bv.w, \
        bperm(idxR, Bv.x), bperm(idxR, Bv.y), bperm(idxR, Bv.z), bperm(idxR, Bv.w)}; \
    const float a[4] = {A.x, A.y, A.z, A.w}; \
    _Pragma("unroll") \
    for (int dj = 0; dj < 9; ++dj) { \
        _Pragma("unroll") \
        for (int p = 0; p < 4; ++p) \
            acc[dj][p] = fmaf(a[p], w[dj + p], acc[dj][p]); \
    } } while (0)

    // 3 rotating sets; load->use distance = 2 compute bodies.
    f32x4 xa, xb, ya, yb, za, zb;
    LOADSET(xa, xb);                          // ch 0
    LOADSET(ya, yb);                          // ch 1

    for (int g = 0; g < 42; ++g) {            // channels 3g .. 3g+2
        LOADSET(za, zb);                      // ch 3g+2
        COMPSET(xa, xb);                      // ch 3g
        LOADSET(xa, xb);                      // ch 3g+3
        COMPSET(ya, yb);                      // ch 3g+1
        LOADSET(ya, yb);                      // ch 3g+4
        COMPSET(za, zb);                      // ch 3g+2
    }
    COMPSET(xa, xb);                          // ch 126
    COMPSET(ya, yb);                          // ch 127

#undef LOADSET
#undef COMPSET

    if (lane < 56) {
        const float s = 1.0f / 128.0f;
        const bool leftEdge  = (G == 0);
        const bool rightEdge = (G == 111);
#pragma unroll
        for (int dj = 0; dj < 9; ++dj) {
            float o[4];
#pragma unroll
            for (int p = 0; p < 4; ++p) {
                float v = acc[dj][p] * s;
                // out col = 4G + p + dj - 4: left-quad garbage -> dj+p<4,
                // right-quad garbage -> dj+p>7.
                if (dj + p < 4) v = leftEdge  ? 0.f : v;
                if (dj + p > 7) v = rightEdge ? 0.f : v;
                o[p] = v;
            }
            f32x4 ov = {o[0], o[1], o[2], o[3]};
            *(f32x4*)(ob + (size_t)dj * HW) = ov;
        }
    }
}

extern "C" void kernel_launch(void* const* d_in, const int* in_sizes, int n_in,
                              void* d_out, int out_size, void* d_ws, size_t ws_size,
                              hipStream_t stream) {
    const float* feat1 = (const float*)d_in[0];
    const float* feat2 = (const float*)d_in[1];
    float* out = (float*)d_out;
    cv_kernel<<<dim3(4608), dim3(256), 0, stream>>>(feat1, feat2, out);
}